// Round 1
// baseline (354.416 us; speedup 1.0000x reference)
//
#include <hip/hip_runtime.h>
#include <stdint.h>

// TinyMod fused: x[8192,4096] -> (fcin 32x32) -> 32x blockwise Linear(128->128) -> (fcout 32x32)
// BT=8 batch rows/WG, 512 threads (8 waves), grid 1024.
// LDS = 75 KiB -> 2 WGs/CU resident (16 waves/CU). Stage 1 is barrier-free with
// direct global->fragment loads (64B segments, one wave per batch row).

#define BT    8
#define NTHR  512
#define GRID  1024     // 8192 / BT
#define IDIM  4096
#define ODIM  4096

typedef __attribute__((ext_vector_type(8))) __bf16 bf16x8;
typedef __attribute__((ext_vector_type(4))) float  floatx4;

union BF8 { uint32_t w[4]; unsigned short h[8]; bf16x8 v; };

__device__ __forceinline__ unsigned short f2bf(float f) {
    uint32_t u = __builtin_bit_cast(uint32_t, f);
    u += 0x7fffu + ((u >> 16) & 1u);   // RNE
    return (unsigned short)(u >> 16);
}

// ylds[c:32][bt:8][m:128]; (c,bt)-row pitch 132 elems (66 dwords: bank-spreads bt).
// m swizzled in 4-elem (8B) units: unit' = unit ^ (c&7) -> spreads stage-1 write banks
// (16 c-lanes otherwise collapse to 2 banks); per-instruction-uniform c on the read
// side makes the swizzle free for stage-2 reads.
#define YROW 132
__device__ __forceinline__ int yaddr(int c, int bt, int m) {
    return (c * 8 + bt) * YROW + ((((m >> 2) ^ (c & 7))) << 2) + (m & 3);
}
// wch[n':16][bt:8][c:32]; (n',bt)-row pitch 36 elems
#define WROW 36

template<bool WBF16>
__global__ __launch_bounds__(NTHR, 4)     // cap 128 VGPR -> guarantee 2 WGs/CU
void tinymod_fused(const float* __restrict__ x,
                   const float* __restrict__ W_in,
                   const float* __restrict__ b_in,
                   const void*  __restrict__ wmods,
                   const float* __restrict__ b_mods,
                   const float* __restrict__ W_out,
                   const float* __restrict__ b_out,
                   float* __restrict__ out)
{
    __shared__ unsigned short ylds[256 * YROW]    __attribute__((aligned(16))); // 67584 B
    __shared__ unsigned short wch [16 * 8 * WROW] __attribute__((aligned(16))); //  9216 B

    const int tid  = threadIdx.x;
    const int lane = tid & 63;
    const int wave = tid >> 6;      // 0..7
    const int l15  = lane & 15;
    const int grp  = lane >> 4;     // 0..3
    const int row0 = blockIdx.x * BT;

    // ---- tiny operand preloads (held in VGPRs whole kernel) ----
    const float bin0 = b_in[l15],  bin1 = b_in[16 + l15];
    const float bo0  = b_out[l15], bo1  = b_out[16 + l15];
    BF8 winf[2], woutf[2];
    #pragma unroll
    for (int cc = 0; cc < 2; cc++) {
        const float* p = W_in  + (l15 + 16*cc) * 32 + grp * 8;  // B[k=i][col=c]
        const float* q = W_out + (l15 + 16*cc) * 32 + grp * 8;  // B[k=c][col=o]
        #pragma unroll
        for (int j = 0; j < 8; j++) { winf[cc].h[j] = f2bf(p[j]); woutf[cc].h[j] = f2bf(q[j]); }
    }

    // ---------------- Stage 1: x -> y (fcin), barrier-free ----------------
    // wave owns bt = wave. Lane (l15=m', grp=i-quad) loads A[row=m'][k=i] directly:
    // 16 consecutive m per instruction -> 64B segments, each x element loaded once.
    const float* xb = x + (row0 + wave) * IDIM + l15;   // + i*128 + mb*16
    float xr[8];
    #pragma unroll
    for (int j = 0; j < 8; j++) xr[j] = xb[(grp*8 + j) * 128];

    for (int mb = 0; mb < 8; mb++) {
        float xn[8];
        if (mb < 7) {
            #pragma unroll
            for (int j = 0; j < 8; j++) xn[j] = xb[(grp*8 + j) * 128 + (mb + 1) * 16];
        }
        BF8 a;
        #pragma unroll
        for (int j = 0; j < 8; j++) a.h[j] = f2bf(xr[j]);
        #pragma unroll
        for (int cc = 0; cc < 2; cc++) {
            floatx4 acc = {0.f, 0.f, 0.f, 0.f};
            acc = __builtin_amdgcn_mfma_f32_16x16x32_bf16(a.v, winf[cc].v, acc, 0, 0, 0);
            const float bi = cc ? bin1 : bin0;
            unsigned short h[4];
            #pragma unroll
            for (int r = 0; r < 4; r++) h[r] = f2bf(acc[r] + bi);   // D row grp*4+r = m'
            uint2 pk;
            pk.x = (uint32_t)h[0] | ((uint32_t)h[1] << 16);
            pk.y = (uint32_t)h[2] | ((uint32_t)h[3] << 16);
            *(uint2*)&ylds[yaddr(l15 + 16*cc, wave, mb*16 + grp*4)] = pk;
        }
        if (mb < 7) {
            #pragma unroll
            for (int j = 0; j < 8; j++) xr[j] = xn[j];
        }
    }
    __syncthreads();   // the only stage-1 barrier

    // ---------------- Stage 2+3: y -> w -> out, 8 n-blocks of 16 ----------------
    const unsigned short* __restrict__ wm16 = (const unsigned short*)wmods;
    const float*          __restrict__ wm32 = (const float*)wmods;
    const int btA = l15 & 7;   // A-row bt (rows 8..15 duplicate rows 0..7)

    for (int nb = 0; nb < 8; nb++) {
        // stage 2: wave owns c = 4*wave + ci; D[bt(8 of 16)][n'=l15], K=m=128
        floatx4 acc[4];
        float   bm[4];
        #pragma unroll
        for (int ci = 0; ci < 4; ci++) {
            const int c = 4*wave + ci;
            bm[ci] = b_mods[c*128 + nb*16 + l15];
            floatx4 s = {0.f, 0.f, 0.f, 0.f};
            #pragma unroll
            for (int kc = 0; kc < 4; kc++) {
                const int m0 = kc*32 + grp*8;
                BF8 a2;
                const uint2 u0 = *(const uint2*)&ylds[yaddr(c, btA, m0)];
                const uint2 u1 = *(const uint2*)&ylds[yaddr(c, btA, m0 + 4)];
                a2.w[0] = u0.x; a2.w[1] = u0.y; a2.w[2] = u1.x; a2.w[3] = u1.y;
                BF8 b;
                const int wbase = (c*128 + nb*16 + l15)*128 + kc*32 + grp*8;
                if (WBF16) {
                    const uint4 bv = *(const uint4*)&wm16[wbase];
                    b.w[0] = bv.x; b.w[1] = bv.y; b.w[2] = bv.z; b.w[3] = bv.w;
                } else {
                    const float* wp = wm32 + wbase;
                    #pragma unroll
                    for (int j = 0; j < 8; j++) b.h[j] = f2bf(wp[j]);
                }
                s = __builtin_amdgcn_mfma_f32_16x16x32_bf16(a2.v, b.v, s, 0, 0, 0);
            }
            acc[ci] = s;
        }
        // w -> wch: only rows 0..7 are real (grp<2); pack the wave's 4 contiguous c
        if (grp < 2) {
            #pragma unroll
            for (int r = 0; r < 4; r++) {
                const int bt = grp*4 + r;
                unsigned short h[4];
                #pragma unroll
                for (int ci = 0; ci < 4; ci++) h[ci] = f2bf(acc[ci][r] + bm[ci]);
                uint2 pk;
                pk.x = (uint32_t)h[0] | ((uint32_t)h[1] << 16);
                pk.y = (uint32_t)h[2] | ((uint32_t)h[3] << 16);
                *(uint2*)&wch[(l15*8 + bt)*WROW + 4*wave] = pk;
            }
        }
        __syncthreads();   // wch ready

        // stage 3 A-frag: wave owns n' = 2*wave + {0,1}; rows=(nlo,bt), K=c=32
        const int np = 2*wave + (l15 >> 3);
        BF8 a3;
        {
            const int off = (np*8 + btA)*WROW + grp*8;
            const uint2 u0 = *(const uint2*)&wch[off];
            const uint2 u1 = *(const uint2*)&wch[off + 4];
            a3.w[0] = u0.x; a3.w[1] = u0.y; a3.w[2] = u1.x; a3.w[3] = u1.y;
        }
        __syncthreads();   // wch consumed; MFMA+stores below overlap next nb's stage 2

        #pragma unroll
        for (int oc = 0; oc < 2; oc++) {
            floatx4 v = {0.f, 0.f, 0.f, 0.f};
            v = __builtin_amdgcn_mfma_f32_16x16x32_bf16(a3.v, woutf[oc].v, v, 0, 0, 0);
            const float bo = oc ? bo1 : bo0;
            #pragma unroll
            for (int r = 0; r < 4; r++) {
                const int R   = grp*4 + r;         // D row -> (nlo, bt)
                const int nlo = R >> 3;
                const int bt  = R & 7;
                out[(row0 + bt)*ODIM + (nb*16 + 2*wave + nlo)*32 + oc*16 + l15] = v[r] + bo;
            }
        }
    }
}

// prologue: W_mods fp32 -> bf16 into workspace (2 MiB -> 1 MiB, L2/L3 resident)
__global__ void wmods_to_bf16(const float* __restrict__ w, unsigned short* __restrict__ o) {
    const int i = (blockIdx.x * 256 + threadIdx.x) * 4;
    const float4 f = *(const float4*)(w + i);
    uint2 pk;
    pk.x = (uint32_t)f2bf(f.x) | ((uint32_t)f2bf(f.y) << 16);
    pk.y = (uint32_t)f2bf(f.z) | ((uint32_t)f2bf(f.w) << 16);
    *(uint2*)(o + i) = pk;
}

extern "C" void kernel_launch(void* const* d_in, const int* in_sizes, int n_in,
                              void* d_out, int out_size, void* d_ws, size_t ws_size,
                              hipStream_t stream)
{
    const float* x     = (const float*)d_in[0];
    const float* W_in  = (const float*)d_in[1];
    const float* b_in  = (const float*)d_in[2];
    const float* Wm    = (const float*)d_in[3];
    const float* b_m   = (const float*)d_in[4];
    const float* W_out = (const float*)d_in[5];
    const float* b_out = (const float*)d_in[6];
    float* out = (float*)d_out;

    const size_t wm_elems = 32u * 128u * 128u;   // 524288
    if (ws_size >= wm_elems * sizeof(unsigned short)) {
        unsigned short* wbf = (unsigned short*)d_ws;
        wmods_to_bf16<<<(int)(wm_elems / (256 * 4)), 256, 0, stream>>>(Wm, wbf);
        tinymod_fused<true><<<GRID, NTHR, 0, stream>>>(x, W_in, b_in, (const void*)wbf,
                                                       b_m, W_out, b_out, out);
    } else {
        tinymod_fused<false><<<GRID, NTHR, 0, stream>>>(x, W_in, b_in, (const void*)Wm,
                                                        b_m, W_out, b_out, out);
    }
}

// Round 2
// 306.359 us; speedup vs baseline: 1.1569x; 1.1569x over previous
//
#include <hip/hip_runtime.h>
#include <stdint.h>

// TinyMod fused: x[8192,4096] -> (fcin 32x32) -> 32x blockwise Linear(128->128) -> (fcout 32x32)
// BT=16 rows/WG, 1024 threads (16 waves), grid 512. LDS 158.5 KB -> 1 WG/CU but 16 waves/CU
// (vs Round-0's 8) with ZERO wasted MFMA rows (vs Round-1's half-empty stage-2 tiles).
// Stage-2 A-fragments hoisted to VGPRs once (kills the 8x redundant per-nb LDS re-reads);
// stage 2 is then a pure L2-load -> MFMA pipeline overlappable with stage-3 across barriers.

#define BT    16
#define NTHR  1024
#define GRID  512      // 8192 / BT
#define IDIM  4096
#define ODIM  4096

typedef __attribute__((ext_vector_type(8))) __bf16 bf16x8;
typedef __attribute__((ext_vector_type(4))) float  floatx4;

union BF8 { uint32_t w[4]; unsigned short h[8]; bf16x8 v; };

__device__ __forceinline__ unsigned short f2bf(float f) {
    uint32_t u = __builtin_bit_cast(uint32_t, f);
    u += 0x7fffu + ((u >> 16) & 1u);   // RNE
    return (unsigned short)(u >> 16);
}

// ylds[c:32][bt:16][m:128]: bt-pitch 136 elems (68 dw), c-pitch 2184 elems (1092 dw).
// Both pitches are multiples of 8 elems -> 16B-aligned ds_read_b128 for stage-2 A-frags.
// Bank math: stage-1 b64 writes p=4*l15+2*grp (4/bank = b64 floor); stage-2 b128 reads
// p=4*(l15+grp) (8/bank = b128 floor) -> both conflict-free.
#define YP_BT 136
#define YP_C  2184     // 16*136 + 8 (the +8 keeps c-lanes bank-spread: 1092 dw = 4 mod 32)
// wch[n':16][bt:16][c:32]: bt-pitch 36, n'-pitch 584 (R0-proven layout)
#define WP_BT 36
#define WP_N  584

template<bool WBF16>
__global__ __launch_bounds__(NTHR, 4)    // 16 waves/WG, cap 128 VGPR
void tinymod_fused(const float* __restrict__ x,
                   const float* __restrict__ W_in,
                   const float* __restrict__ b_in,
                   const void*  __restrict__ wmods,
                   const float* __restrict__ b_mods,
                   const float* __restrict__ W_out,
                   const float* __restrict__ b_out,
                   float* __restrict__ out)
{
    __shared__ unsigned short ylds[32 * YP_C] __attribute__((aligned(16))); // 139,776 B
    __shared__ unsigned short wch [16 * WP_N] __attribute__((aligned(16))); //  18,688 B

    const int tid  = threadIdx.x;
    const int lane = tid & 63;
    const int wave = tid >> 6;      // 0..15
    const int l15  = lane & 15;
    const int grp  = lane >> 4;     // 0..3
    const int row0 = blockIdx.x * BT;

    // ---- tiny operand preloads (held in VGPRs whole kernel) ----
    const float bin0 = b_in[l15],  bin1 = b_in[16 + l15];
    const float bo0  = b_out[l15], bo1  = b_out[16 + l15];
    BF8 winf[2], woutf[2];
    #pragma unroll
    for (int cc = 0; cc < 2; cc++) {
        const float* p = W_in  + (l15 + 16*cc) * 32 + grp * 8;  // B[k=i][col=c]
        const float* q = W_out + (l15 + 16*cc) * 32 + grp * 8;  // B[k=c][col=o]
        #pragma unroll
        for (int j = 0; j < 8; j++) { winf[cc].h[j] = f2bf(p[j]); woutf[cc].h[j] = f2bf(q[j]); }
    }

    // ---------------- Stage 1: x -> y (fcin), barrier-free ----------------
    // wave owns bt = wave. Lane (l15=m-row, grp=i-quad) loads A[row=m'][k=i] directly:
    // 16 consecutive m per instruction -> 64B segments, each x element loaded once.
    const float* xb = x + (row0 + wave) * IDIM + l15;   // + i*128 + mb*16
    float xr[8];
    #pragma unroll
    for (int j = 0; j < 8; j++) xr[j] = xb[(grp*8 + j) * 128];

    for (int mb = 0; mb < 8; mb++) {
        float xn[8];
        if (mb < 7) {
            #pragma unroll
            for (int j = 0; j < 8; j++) xn[j] = xb[(grp*8 + j) * 128 + (mb + 1) * 16];
        }
        BF8 a;
        #pragma unroll
        for (int j = 0; j < 8; j++) a.h[j] = f2bf(xr[j]);
        #pragma unroll
        for (int cc = 0; cc < 2; cc++) {
            floatx4 acc = {0.f, 0.f, 0.f, 0.f};
            acc = __builtin_amdgcn_mfma_f32_16x16x32_bf16(a.v, winf[cc].v, acc, 0, 0, 0);
            const float bi = cc ? bin1 : bin0;
            unsigned short h[4];
            #pragma unroll
            for (int r = 0; r < 4; r++) h[r] = f2bf(acc[r] + bi);   // D row grp*4+r = m
            uint2 pk;
            pk.x = (uint32_t)h[0] | ((uint32_t)h[1] << 16);
            pk.y = (uint32_t)h[2] | ((uint32_t)h[3] << 16);
            // y[c][bt=wave][m = mb*16 + grp*4 + r] -- 4 consecutive m in one b64
            *(uint2*)&ylds[(l15 + 16*cc)*YP_C + wave*YP_BT + mb*16 + grp*4] = pk;
        }
        if (mb < 7) {
            #pragma unroll
            for (int j = 0; j < 8; j++) xr[j] = xn[j];
        }
    }
    __syncthreads();   // the only stage-1 barrier

    // ---- hoist stage-2 A-fragments: wave owns c = 2*wave + {0,1}; A[bt=l15][k=m] ----
    // Read ONCE (8 x ds_read_b128), reused for all 8 n-blocks (was 8x redundant before).
    BF8 af[2][4];
    #pragma unroll
    for (int ci = 0; ci < 2; ci++) {
        const int c = 2*wave + ci;
        #pragma unroll
        for (int kc = 0; kc < 4; kc++) {
            const uint4 v = *(const uint4*)&ylds[c*YP_C + l15*YP_BT + kc*32 + grp*8];
            af[ci][kc].w[0] = v.x; af[ci][kc].w[1] = v.y;
            af[ci][kc].w[2] = v.z; af[ci][kc].w[3] = v.w;
        }
    }

    // ---------------- Stage 2+3: y -> w -> out, 8 n-blocks of 16 ----------------
    const unsigned short* __restrict__ wm16 = (const unsigned short*)wmods;
    const float*          __restrict__ wm32 = (const float*)wmods;

    for (int nb = 0; nb < 8; nb++) {
        // stage 2: wave owns c = 2*wave + ci; D[bt:16 full][n'=l15], K=m=128.
        // No LDS reads here -> B-loads (L2) can pipeline across the previous barrier.
        floatx4 acc[2];
        float   bm[2];
        #pragma unroll
        for (int ci = 0; ci < 2; ci++) {
            const int c = 2*wave + ci;
            bm[ci] = b_mods[c*128 + nb*16 + l15];
            floatx4 s = {0.f, 0.f, 0.f, 0.f};
            #pragma unroll
            for (int kc = 0; kc < 4; kc++) {
                BF8 b;
                const int wbase = (c*128 + nb*16 + l15)*128 + kc*32 + grp*8;
                if (WBF16) {
                    const uint4 bv = *(const uint4*)&wm16[wbase];
                    b.w[0] = bv.x; b.w[1] = bv.y; b.w[2] = bv.z; b.w[3] = bv.w;
                } else {
                    const float* wp = wm32 + wbase;
                    #pragma unroll
                    for (int j = 0; j < 8; j++) b.h[j] = f2bf(wp[j]);
                }
                s = __builtin_amdgcn_mfma_f32_16x16x32_bf16(af[ci][kc].v, b.v, s, 0, 0, 0);
            }
            acc[ci] = s;
        }
        // w -> wch: pack the wave's 2 contiguous c into one b32 write
        #pragma unroll
        for (int r = 0; r < 4; r++) {
            unsigned short h0 = f2bf(acc[0][r] + bm[0]);
            unsigned short h1 = f2bf(acc[1][r] + bm[1]);
            const uint32_t pk = (uint32_t)h0 | ((uint32_t)h1 << 16);
            // wch[n'=l15][bt=grp*4+r][c=2*wave+{0,1}]
            *(uint32_t*)&wch[l15*WP_N + (grp*4 + r)*WP_BT + 2*wave] = pk;
        }
        __syncthreads();   // wch ready

        // stage 3 A-frag: wave owns n' = wave; A[bt=l15][k=c:32]
        BF8 a3;
        {
            const int off = wave*WP_N + l15*WP_BT + grp*8;
            const uint2 u0 = *(const uint2*)&wch[off];
            const uint2 u1 = *(const uint2*)&wch[off + 4];
            a3.w[0] = u0.x; a3.w[1] = u0.y; a3.w[2] = u1.x; a3.w[3] = u1.y;
        }
        __syncthreads();   // wch consumed; MFMA+stores below overlap next nb's stage 2

        #pragma unroll
        for (int oc = 0; oc < 2; oc++) {
            floatx4 v = {0.f, 0.f, 0.f, 0.f};
            v = __builtin_amdgcn_mfma_f32_16x16x32_bf16(a3.v, woutf[oc].v, v, 0, 0, 0);
            const float bo = oc ? bo1 : bo0;
            float* po = out + row0*ODIM + (nb*16 + wave)*32 + oc*16 + l15;
            #pragma unroll
            for (int r = 0; r < 4; r++) {
                const int bt = grp*4 + r;          // D row = bt
                po[bt*ODIM] = v[r] + bo;           // 16 lanes x 4B = 64B segments
            }
        }
    }
}

// prologue: W_mods fp32 -> bf16 into workspace (2 MiB -> 1 MiB, L2/L3 resident)
__global__ void wmods_to_bf16(const float* __restrict__ w, unsigned short* __restrict__ o) {
    const int i = (blockIdx.x * 256 + threadIdx.x) * 4;
    const float4 f = *(const float4*)(w + i);
    uint2 pk;
    pk.x = (uint32_t)f2bf(f.x) | ((uint32_t)f2bf(f.y) << 16);
    pk.y = (uint32_t)f2bf(f.z) | ((uint32_t)f2bf(f.w) << 16);
    *(uint2*)(o + i) = pk;
}

extern "C" void kernel_launch(void* const* d_in, const int* in_sizes, int n_in,
                              void* d_out, int out_size, void* d_ws, size_t ws_size,
                              hipStream_t stream)
{
    const float* x     = (const float*)d_in[0];
    const float* W_in  = (const float*)d_in[1];
    const float* b_in  = (const float*)d_in[2];
    const float* Wm    = (const float*)d_in[3];
    const float* b_m   = (const float*)d_in[4];
    const float* W_out = (const float*)d_in[5];
    const float* b_out = (const float*)d_in[6];
    float* out = (float*)d_out;

    const size_t wm_elems = 32u * 128u * 128u;   // 524288
    if (ws_size >= wm_elems * sizeof(unsigned short)) {
        unsigned short* wbf = (unsigned short*)d_ws;
        wmods_to_bf16<<<(int)(wm_elems / (256 * 4)), 256, 0, stream>>>(Wm, wbf);
        tinymod_fused<true><<<GRID, NTHR, 0, stream>>>(x, W_in, b_in, (const void*)wbf,
                                                       b_m, W_out, b_out, out);
    } else {
        tinymod_fused<false><<<GRID, NTHR, 0, stream>>>(x, W_in, b_in, (const void*)Wm,
                                                        b_m, W_out, b_out, out);
    }
}

// Round 3
// 304.982 us; speedup vs baseline: 1.1621x; 1.0045x over previous
//
#include <hip/hip_runtime.h>
#include <stdint.h>

// TinyMod fused: x[8192,4096] -> (fcin 32x32) -> 32x blockwise Linear(128->128) -> (fcout 32x32)
// BT=16 rows/WG, 1024 threads (16 waves), grid 512.
// R3: all __syncthreads (vmcnt(0)-draining) replaced with raw s_barrier + lgkmcnt(0) only,
// so HBM stores and W_mods loads stay in flight across barriers (T4 mechanism).
// wch double-buffered inside dead ylds space (alias) -> 1 barrier per nb, 10 total (was 17).
// Stage-2 B-fragments batch-loaded (8 x b128 = 32 VGPR) before the MFMAs.
// Native __bf16 casts -> compiler emits v_cvt_pk_bf16_f32.

#define BT    16
#define NTHR  1024
#define GRID  512      // 8192 / BT
#define IDIM  4096
#define ODIM  4096

typedef __attribute__((ext_vector_type(8))) __bf16 bf16x8;
typedef __attribute__((ext_vector_type(4))) float  floatx4;

union BF8 { uint32_t w[4]; unsigned short h[8]; bf16x8 v; };

__device__ __forceinline__ unsigned short f2bf(float f) {
    return __builtin_bit_cast(unsigned short, (__bf16)f);   // RNE, compiler can pack-pair
}

// ylds[c:32][bt:16][m:128]: bt-pitch 136, c-pitch 2184 (16B-aligned b128 frags, conflict-free
// per R2 bank math). Dead after the af-hoist -> its space is reused for the wch ping-pong.
#define YP_BT 136
#define YP_C  2184
// wch[n':16][bt:16][c:32]: bt-pitch 36, n'-pitch 584; two 18,688 B buffers aliased into ylds.
#define WP_BT 36
#define WP_N  584
#define WCH_HALF (16 * WP_N)    // 9344 elems per buffer

// Raw barrier: LDS ordering only. NO vmcnt drain -> stores/loads pipeline across.
__device__ __forceinline__ void bar_lgkm() {
    asm volatile("s_waitcnt lgkmcnt(0)" ::: "memory");
    __builtin_amdgcn_s_barrier();
    __builtin_amdgcn_sched_barrier(0);
}

template<bool WBF16>
__global__ __launch_bounds__(NTHR, 4)    // 1024-thr WG => VGPR cap 128
void tinymod_fused(const float* __restrict__ x,
                   const float* __restrict__ W_in,
                   const float* __restrict__ b_in,
                   const void*  __restrict__ wmods,
                   const float* __restrict__ b_mods,
                   const float* __restrict__ W_out,
                   const float* __restrict__ b_out,
                   float* __restrict__ out)
{
    __shared__ unsigned short ylds[32 * YP_C] __attribute__((aligned(16))); // 139,776 B
    unsigned short* const wch = ylds;   // alias: valid once af-hoist reads are complete

    const int tid  = threadIdx.x;
    const int lane = tid & 63;
    const int wave = tid >> 6;      // 0..15
    const int l15  = lane & 15;
    const int grp  = lane >> 4;     // 0..3
    const int row0 = blockIdx.x * BT;

    // ---- tiny operand preloads (held in VGPRs whole kernel) ----
    const float bin0 = b_in[l15],  bin1 = b_in[16 + l15];
    const float bo0  = b_out[l15], bo1  = b_out[16 + l15];
    BF8 winf[2], woutf[2];
    #pragma unroll
    for (int cc = 0; cc < 2; cc++) {
        const float* p = W_in  + (l15 + 16*cc) * 32 + grp * 8;  // B[k=i][col=c]
        const float* q = W_out + (l15 + 16*cc) * 32 + grp * 8;  // B[k=c][col=o]
        #pragma unroll
        for (int j = 0; j < 8; j++) { winf[cc].h[j] = f2bf(p[j]); woutf[cc].h[j] = f2bf(q[j]); }
    }

    // ---------------- Stage 1: x -> y (fcin), barrier-free ----------------
    // wave owns bt = wave. Lane (l15=m-row, grp=i-quad) loads A[row=m'][k=i] directly:
    // 16 consecutive m per instruction -> 64B segments, each x element loaded once.
    const float* xb = x + (row0 + wave) * IDIM + l15;   // + i*128 + mb*16
    float xr[8];
    #pragma unroll
    for (int j = 0; j < 8; j++) xr[j] = xb[(grp*8 + j) * 128];

    for (int mb = 0; mb < 8; mb++) {
        float xn[8];
        if (mb < 7) {
            #pragma unroll
            for (int j = 0; j < 8; j++) xn[j] = xb[(grp*8 + j) * 128 + (mb + 1) * 16];
        }
        BF8 a;
        #pragma unroll
        for (int j = 0; j < 8; j++) a.h[j] = f2bf(xr[j]);
        #pragma unroll
        for (int cc = 0; cc < 2; cc++) {
            floatx4 acc = {0.f, 0.f, 0.f, 0.f};
            acc = __builtin_amdgcn_mfma_f32_16x16x32_bf16(a.v, winf[cc].v, acc, 0, 0, 0);
            const float bi = cc ? bin1 : bin0;
            unsigned short h[4];
            #pragma unroll
            for (int r = 0; r < 4; r++) h[r] = f2bf(acc[r] + bi);   // D row grp*4+r = m
            uint2 pk;
            pk.x = (uint32_t)h[0] | ((uint32_t)h[1] << 16);
            pk.y = (uint32_t)h[2] | ((uint32_t)h[3] << 16);
            *(uint2*)&ylds[(l15 + 16*cc)*YP_C + wave*YP_BT + mb*16 + grp*4] = pk;
        }
        if (mb < 7) {
            #pragma unroll
            for (int j = 0; j < 8; j++) xr[j] = xn[j];
        }
    }
    bar_lgkm();     // y ready (stage-1 ds_writes complete)

    // ---- hoist stage-2 A-fragments: wave owns c = 2*wave + {0,1}; A[bt=l15][k=m] ----
    BF8 af[2][4];
    #pragma unroll
    for (int ci = 0; ci < 2; ci++) {
        const int c = 2*wave + ci;
        #pragma unroll
        for (int kc = 0; kc < 4; kc++) {
            const uint4 v = *(const uint4*)&ylds[c*YP_C + l15*YP_BT + kc*32 + grp*8];
            af[ci][kc].w[0] = v.x; af[ci][kc].w[1] = v.y;
            af[ci][kc].w[2] = v.z; af[ci][kc].w[3] = v.w;
        }
    }
    bar_lgkm();     // af reads drained -> ylds space now reusable as wch ping-pong

    // ---------------- Stage 2+3: y -> w -> out, 8 n-blocks of 16 ----------------
    const unsigned short* __restrict__ wm16 = (const unsigned short*)wmods;
    const float*          __restrict__ wm32 = (const float*)wmods;

    for (int nb = 0; nb < 8; nb++) {
        unsigned short* const wchb = wch + (nb & 1) * WCH_HALF;

        // stage 2: batch-issue ALL B-fragments (8 x b128, 32 VGPR) before any MFMA ->
        // one overlapped L2-latency window per nb instead of four chained ones.
        float bm[2];
        BF8 b[2][4];
        #pragma unroll
        for (int ci = 0; ci < 2; ci++) {
            const int c = 2*wave + ci;
            bm[ci] = b_mods[c*128 + nb*16 + l15];
            #pragma unroll
            for (int kc = 0; kc < 4; kc++) {
                const int wbase = (c*128 + nb*16 + l15)*128 + kc*32 + grp*8;
                if (WBF16) {
                    const uint4 bv = *(const uint4*)&wm16[wbase];
                    b[ci][kc].w[0] = bv.x; b[ci][kc].w[1] = bv.y;
                    b[ci][kc].w[2] = bv.z; b[ci][kc].w[3] = bv.w;
                } else {
                    const float* wp = wm32 + wbase;
                    #pragma unroll
                    for (int j = 0; j < 8; j++) b[ci][kc].h[j] = f2bf(wp[j]);
                }
            }
        }
        floatx4 acc[2];
        #pragma unroll
        for (int ci = 0; ci < 2; ci++) {
            floatx4 s = {0.f, 0.f, 0.f, 0.f};
            #pragma unroll
            for (int kc = 0; kc < 4; kc++)
                s = __builtin_amdgcn_mfma_f32_16x16x32_bf16(af[ci][kc].v, b[ci][kc].v, s, 0, 0, 0);
            acc[ci] = s;
        }
        // w -> wch[nb&1]: pack the wave's 2 contiguous c into one b32 write
        #pragma unroll
        for (int r = 0; r < 4; r++) {
            const unsigned short h0 = f2bf(acc[0][r] + bm[0]);
            const unsigned short h1 = f2bf(acc[1][r] + bm[1]);
            const uint32_t pk = (uint32_t)h0 | ((uint32_t)h1 << 16);
            *(uint32_t*)&wchb[l15*WP_N + (grp*4 + r)*WP_BT + 2*wave] = pk;
        }
        bar_lgkm();     // wch[nb&1] ready -- the ONLY barrier per nb (double-buffered:
                        // next nb writes the other half while this one is consumed)

        // stage 3: wave owns n' = wave; A[bt=l15][k=c:32]
        BF8 a3;
        {
            const int off = wave*WP_N + l15*WP_BT + grp*8;
            const uint2 u0 = *(const uint2*)&wchb[off];
            const uint2 u1 = *(const uint2*)&wchb[off + 4];
            a3.w[0] = u0.x; a3.w[1] = u0.y; a3.w[2] = u1.x; a3.w[3] = u1.y;
        }
        #pragma unroll
        for (int oc = 0; oc < 2; oc++) {
            floatx4 v = {0.f, 0.f, 0.f, 0.f};
            v = __builtin_amdgcn_mfma_f32_16x16x32_bf16(a3.v, woutf[oc].v, v, 0, 0, 0);
            const float bo = oc ? bo1 : bo0;
            float* po = out + row0*ODIM + (nb*16 + wave)*32 + oc*16 + l15;
            #pragma unroll
            for (int r = 0; r < 4; r++) {
                const int bt = grp*4 + r;          // D row = bt
                po[bt*ODIM] = v[r] + bo;           // 16 lanes x 4B = 64B segments;
                                                   // drains in background (no vmcnt(0) anywhere)
            }
        }
    }
}

// prologue: W_mods fp32 -> bf16 into workspace (2 MiB -> 1 MiB, L2/L3 resident)
__global__ void wmods_to_bf16(const float* __restrict__ w, unsigned short* __restrict__ o) {
    const int i = (blockIdx.x * 256 + threadIdx.x) * 4;
    const float4 f = *(const float4*)(w + i);
    uint2 pk;
    pk.x = (uint32_t)f2bf(f.x) | ((uint32_t)f2bf(f.y) << 16);
    pk.y = (uint32_t)f2bf(f.z) | ((uint32_t)f2bf(f.w) << 16);
    *(uint2*)(o + i) = pk;
}

extern "C" void kernel_launch(void* const* d_in, const int* in_sizes, int n_in,
                              void* d_out, int out_size, void* d_ws, size_t ws_size,
                              hipStream_t stream)
{
    const float* x     = (const float*)d_in[0];
    const float* W_in  = (const float*)d_in[1];
    const float* b_in  = (const float*)d_in[2];
    const float* Wm    = (const float*)d_in[3];
    const float* b_m   = (const float*)d_in[4];
    const float* W_out = (const float*)d_in[5];
    const float* b_out = (const float*)d_in[6];
    float* out = (float*)d_out;

    const size_t wm_elems = 32u * 128u * 128u;   // 524288
    if (ws_size >= wm_elems * sizeof(unsigned short)) {
        unsigned short* wbf = (unsigned short*)d_ws;
        wmods_to_bf16<<<(int)(wm_elems / (256 * 4)), 256, 0, stream>>>(Wm, wbf);
        tinymod_fused<true><<<GRID, NTHR, 0, stream>>>(x, W_in, b_in, (const void*)wbf,
                                                       b_m, W_out, b_out, out);
    } else {
        tinymod_fused<false><<<GRID, NTHR, 0, stream>>>(x, W_in, b_in, (const void*)Wm,
                                                        b_m, W_out, b_out, out);
    }
}